// Round 3
// baseline (629.972 us; speedup 1.0000x reference)
//
#include <hip/hip_runtime.h>

typedef short s8v  __attribute__((ext_vector_type(8)));
typedef float f4v  __attribute__((ext_vector_type(4)));
typedef int   v2i  __attribute__((ext_vector_type(2)));
typedef float v2f  __attribute__((ext_vector_type(2)));
typedef float v4f  __attribute__((ext_vector_type(4)));

#define NNODES 8192
#define FDIM   256

__device__ __forceinline__ float bf2f(unsigned short u) {
    unsigned int x = ((unsigned int)u) << 16;
    return __builtin_bit_cast(float, x);
}
__device__ __forceinline__ unsigned short f2bf(float f) {
    unsigned int x = __builtin_bit_cast(unsigned int, f);
    x += 0x7fffu + ((x >> 16) & 1u);
    return (unsigned short)(x >> 16);
}

// ---------------- Kernel 0: WT[n][k] = bf16(W[k][n]), W fp32 256x256 ----------------
__global__ __launch_bounds__(256) void wt_kernel(const float* __restrict__ W,
                                                 unsigned short* __restrict__ WT) {
    int idx = blockIdx.x * 256 + threadIdx.x;
    int r = idx >> 8, c = idx & 255;
    WT[c * 256 + r] = f2bf(W[r * 256 + c]);
}

// ---------------- Kernel 0b: v1 = W @ a[:256], v2 = W @ a[256:] (fp32 exact) ----------------
__global__ __launch_bounds__(256) void wv_kernel(const float* __restrict__ W,
                                                 const float* __restrict__ a,
                                                 float* __restrict__ v1, float* __restrict__ v2) {
    int k = threadIdx.x;  // grid = 1 block
    float acc1 = 0.f, acc2 = 0.f;
    const float* wrow = W + (size_t)k * FDIM;
    for (int n = 0; n < FDIM; ++n) {
        float w = wrow[n];
        acc1 += w * a[n];          // a[n] wave-uniform -> scalar load
        acc2 += w * a[FDIM + n];
    }
    v1[k] = acc1;
    v2[k] = acc2;
}

// ---------------- Kernel 1: WhT = bf16((h@W)^T); s1/s2 = h@v (pure fp32) ----------------
// grid 128 blocks x 256 threads. Block: 64 rows x 256 cols, K=256. h fp32.
__global__ __launch_bounds__(256) void wh_kernel(
    const float* __restrict__ h, const unsigned short* __restrict__ WT,
    const float* __restrict__ v1, const float* __restrict__ v2,
    unsigned short* __restrict__ WhT,
    float* __restrict__ s1, float* __restrict__ s2)
{
    __shared__ float v1_lds[FDIM], v2_lds[FDIM];
    int tid = threadIdx.x;
    v1_lds[tid] = v1[tid];
    v2_lds[tid] = v2[tid];
    __syncthreads();

    int w = tid >> 6, lane = tid & 63, q = lane >> 4, l15 = lane & 15;
    int i_base = blockIdx.x * 64 + w * 16;

    f4v acc[16] = {};
    float s1p = 0.f, s2p = 0.f;

    for (int k0 = 0; k0 < 256; k0 += 32) {
        // A frag: A[m=l15][k=q*8+j] = h[i_base+l15][k0+q*8+j]  (fp32 -> bf16)
        const float* hp = h + (size_t)(i_base + l15) * FDIM + k0 + q * 8;
        f4v h0 = *(const f4v*)hp;
        f4v h1 = *(const f4v*)(hp + 4);
        s8v af;
#pragma unroll
        for (int j = 0; j < 4; ++j) {
            af[j]     = (short)f2bf(h0[j]);
            af[4 + j] = (short)f2bf(h1[j]);
            s1p += h0[j] * v1_lds[k0 + q * 8 + j] + h1[j] * v1_lds[k0 + q * 8 + 4 + j];
            s2p += h0[j] * v2_lds[k0 + q * 8 + j] + h1[j] * v2_lds[k0 + q * 8 + 4 + j];
        }
#pragma unroll
        for (int t = 0; t < 16; ++t) {
            // B frag: B[k=q*8+j][n=16t+l15] = W[k][n] = WT[n][k]
            s8v bf = *(const s8v*)(WT + (size_t)(t * 16 + l15) * FDIM + k0 + q * 8);
            acc[t] = __builtin_amdgcn_mfma_f32_16x16x32_bf16(af, bf, acc[t], 0, 0, 0);
        }
    }

    // reduce s1p/s2p across the 4 quads (lanes sharing l15): full fp32 row dot
    s1p += __shfl_xor(s1p, 16, 64);
    s1p += __shfl_xor(s1p, 32, 64);
    s2p += __shfl_xor(s2p, 16, 64);
    s2p += __shfl_xor(s2p, 32, 64);
    if (lane < 16) {
        s1[i_base + lane] = s1p;
        s2[i_base + lane] = s2p;
    }

    // store WhT[n][i], n = col = 16t+l15, i = row = i_base + q*4 + r
#pragma unroll
    for (int t = 0; t < 16; ++t)
#pragma unroll
        for (int r = 0; r < 4; ++r)
            WhT[(size_t)(t * 16 + l15) * NNODES + i_base + q * 4 + r] = f2bf(acc[t][r]);
}

// ---------------- Kernel 2: fused masked-softmax attention @ Wh ----------------
// grid 512 blocks x 256 threads. Block: 16 rows x 256 cols, K=8192 (full sweep).
__global__ __launch_bounds__(256) void attn_kernel(
    const int* __restrict__ adj, const unsigned short* __restrict__ WhT,
    const float* __restrict__ s1, const float* __restrict__ s2,
    float* __restrict__ out)
{
    __shared__ float s2_lds[NNODES];
    __shared__ unsigned short P_lds[16 * 32];
    __shared__ float dsum_lds[16][16];
    __shared__ float rinv_lds[16];

    int tid = threadIdx.x;
    int blk = blockIdx.x;

    // stage s2 (32 KB fp32) into LDS
    {
        const v4f* src = (const v4f*)s2;
        v4f* dst = (v4f*)s2_lds;
        for (int i = tid; i < NNODES / 4; i += 256) dst[i] = src[i];
    }

    int m = tid >> 4;            // P-tile row 0..15
    int kph = (tid & 15) * 2;    // k phase within 32-chunk (2 elems/thread)
    int row_g = blk * 16 + m;
    float s1v = s1[row_g];
    const int* arow = adj + (size_t)row_g * NNODES;

    int w = tid >> 6, lane = tid & 63, q = lane >> 4, l15 = lane & 15;
    const unsigned short* bbase[4];
#pragma unroll
    for (int t = 0; t < 4; ++t)
        bbase[t] = WhT + (size_t)(w * 64 + t * 16 + l15) * NNODES + q * 8;

    f4v acc[4] = {};
    float dsum = 0.0f;

    // depth-2 adj prefetch (nontemporal: don't evict L2-resident WhT)
    v2i pf0 = __builtin_nontemporal_load((const v2i*)(arow + kph));
    v2i pf1 = __builtin_nontemporal_load((const v2i*)(arow + 32 + kph));

    __syncthreads();  // s2_lds ready

    for (int step = 0; step < 256; ++step) {
        int k0 = step * 32;
        // B frags for this step (L2-resident WhT), issued early
        s8v bf[4];
#pragma unroll
        for (int t = 0; t < 4; ++t) bf[t] = *(const s8v*)(bbase[t] + k0);

        v2i a2 = pf0;
        pf0 = pf1;
        int nk = (step < 254) ? (k0 + 64 + kph) : kph;  // keep address in-bounds
        pf1 = __builtin_nontemporal_load((const v2i*)(arow + nk));

        v2f s2c = *(const v2f*)&s2_lds[k0 + kph];
        unsigned short pb[2];
#pragma unroll
        for (int j = 0; j < 2; ++j) {
            float x = s1v + s2c[j];
            float e = fmaxf(x, 0.2f * x);   // leaky_relu slope 0.2
            float pe = __expf(e);           // |e| <~ 6: no max-subtraction needed
            float p = (a2[j] > 0) ? pe : 0.0f;
            pb[j] = f2bf(p);
            dsum += bf2f(pb[j]);            // denominator from rounded weights
        }
        unsigned int pk = (unsigned int)pb[0] | ((unsigned int)pb[1] << 16);

        __syncthreads();  // prior A-frag reads complete
        *(unsigned int*)&P_lds[m * 32 + kph] = pk;
        __syncthreads();  // P tile visible

        // A frag: A[m=l15][k=q*8+j]
        s8v a0 = *(const s8v*)&P_lds[l15 * 32 + q * 8];
#pragma unroll
        for (int t = 0; t < 4; ++t)
            acc[t] = __builtin_amdgcn_mfma_f32_16x16x32_bf16(a0, bf[t], acc[t], 0, 0, 0);
    }

    // denominator reduce: thread (m, tid&15) holds partial over its k-phase
    dsum_lds[m][tid & 15] = dsum;
    __syncthreads();
    if (tid < 16) {
        float d = 0.f;
#pragma unroll
        for (int j = 0; j < 16; ++j) d += dsum_lds[tid][j];
        rinv_lds[tid] = 1.0f / fmaxf(d, 1e-30f);
    }
    __syncthreads();

    // epilogue: D[row = q*4 + r][col = w*64 + t*16 + l15], fp32 output
#pragma unroll
    for (int r = 0; r < 4; ++r) {
        int rl = q * 4 + r;
        float ri = rinv_lds[rl];
        size_t orow = (size_t)(blk * 16 + rl) * FDIM;
#pragma unroll
        for (int t = 0; t < 4; ++t)
            out[orow + w * 64 + t * 16 + l15] = acc[t][r] * ri;
    }
}

extern "C" void kernel_launch(void* const* d_in, const int* in_sizes, int n_in,
                              void* d_out, int out_size, void* d_ws, size_t ws_size,
                              hipStream_t stream) {
    const float* h   = (const float*)d_in[0];
    const int*   adj = (const int*)d_in[1];
    const float* W   = (const float*)d_in[2];
    const float* a   = (const float*)d_in[3];
    float* out = (float*)d_out;   // fp32 output per reference dtype

    char* ws = (char*)d_ws;
    unsigned short* WhT = (unsigned short*)ws;                        // 4 MiB
    float* s1 = (float*)(ws + (4u << 20));                            // 32 KiB
    float* s2 = (float*)(ws + (4u << 20) + 32768);                    // 32 KiB
    unsigned short* WT = (unsigned short*)(ws + (4u << 20) + 65536);  // 128 KiB
    float* v1 = (float*)(ws + (4u << 20) + 65536 + 131072);           // 1 KiB
    float* v2 = (float*)(ws + (4u << 20) + 65536 + 131072 + 1024);    // 1 KiB

    hipLaunchKernelGGL(wt_kernel, dim3(256), dim3(256), 0, stream, W, WT);
    hipLaunchKernelGGL(wv_kernel, dim3(1), dim3(256), 0, stream, W, a, v1, v2);
    hipLaunchKernelGGL(wh_kernel, dim3(128), dim3(256), 0, stream, h, WT, v1, v2, WhT, s1, s2);
    hipLaunchKernelGGL(attn_kernel, dim3(512), dim3(256), 0, stream, adj, WhT, s1, s2, out);
}

// Round 4
// 594.463 us; speedup vs baseline: 1.0597x; 1.0597x over previous
//
#include <hip/hip_runtime.h>

typedef short s8v  __attribute__((ext_vector_type(8)));
typedef float f4v  __attribute__((ext_vector_type(4)));
typedef int   v4i  __attribute__((ext_vector_type(4)));
typedef float v4f  __attribute__((ext_vector_type(4)));

#define NNODES 8192
#define FDIM   256

__device__ __forceinline__ float bf2f(unsigned short u) {
    unsigned int x = ((unsigned int)u) << 16;
    return __builtin_bit_cast(float, x);
}
__device__ __forceinline__ unsigned short f2bf(float f) {
    unsigned int x = __builtin_bit_cast(unsigned int, f);
    x += 0x7fffu + ((x >> 16) & 1u);
    return (unsigned short)(x >> 16);
}

// ---------------- Kernel 0: WT[n][k] = bf16(W[k][n]), W fp32 256x256 ----------------
__global__ __launch_bounds__(256) void wt_kernel(const float* __restrict__ W,
                                                 unsigned short* __restrict__ WT) {
    int idx = blockIdx.x * 256 + threadIdx.x;
    int r = idx >> 8, c = idx & 255;
    WT[c * 256 + r] = f2bf(W[r * 256 + c]);
}

// ---------------- Kernel 0b: v1 = W @ a[:256], v2 = W @ a[256:] ----------------
// grid 256 blocks; block b computes v1[b], v2[b] with coalesced loads + LDS reduce.
__global__ __launch_bounds__(256) void wv_kernel(const float* __restrict__ W,
                                                 const float* __restrict__ a,
                                                 float* __restrict__ v1, float* __restrict__ v2) {
    __shared__ float r1[256], r2[256];
    int b = blockIdx.x, n = threadIdx.x;
    float w = W[(size_t)b * FDIM + n];
    r1[n] = w * a[n];
    r2[n] = w * a[FDIM + n];
    __syncthreads();
    for (int off = 128; off > 0; off >>= 1) {
        if (n < off) { r1[n] += r1[n + off]; r2[n] += r2[n + off]; }
        __syncthreads();
    }
    if (n == 0) { v1[b] = r1[0]; v2[b] = r2[0]; }
}

// ---------------- Kernel 1: WhT = bf16((h@W)^T); s1/s2 = h@v (pure fp32) ----------------
// grid 128 blocks x 256 threads. Block: 64 rows x 256 cols, K=256. h fp32.
__global__ __launch_bounds__(256) void wh_kernel(
    const float* __restrict__ h, const unsigned short* __restrict__ WT,
    const float* __restrict__ v1, const float* __restrict__ v2,
    unsigned short* __restrict__ WhT,
    float* __restrict__ s1, float* __restrict__ s2)
{
    __shared__ float v1_lds[FDIM], v2_lds[FDIM];
    int tid = threadIdx.x;
    v1_lds[tid] = v1[tid];
    v2_lds[tid] = v2[tid];
    __syncthreads();

    int w = tid >> 6, lane = tid & 63, q = lane >> 4, l15 = lane & 15;
    int i_base = blockIdx.x * 64 + w * 16;

    f4v acc[16] = {};
    float s1p = 0.f, s2p = 0.f;

    for (int k0 = 0; k0 < 256; k0 += 32) {
        const float* hp = h + (size_t)(i_base + l15) * FDIM + k0 + q * 8;
        f4v h0 = *(const f4v*)hp;
        f4v h1 = *(const f4v*)(hp + 4);
        s8v af;
#pragma unroll
        for (int j = 0; j < 4; ++j) {
            af[j]     = (short)f2bf(h0[j]);
            af[4 + j] = (short)f2bf(h1[j]);
            s1p += h0[j] * v1_lds[k0 + q * 8 + j] + h1[j] * v1_lds[k0 + q * 8 + 4 + j];
            s2p += h0[j] * v2_lds[k0 + q * 8 + j] + h1[j] * v2_lds[k0 + q * 8 + 4 + j];
        }
#pragma unroll
        for (int t = 0; t < 16; ++t) {
            s8v bf = *(const s8v*)(WT + (size_t)(t * 16 + l15) * FDIM + k0 + q * 8);
            acc[t] = __builtin_amdgcn_mfma_f32_16x16x32_bf16(af, bf, acc[t], 0, 0, 0);
        }
    }

    s1p += __shfl_xor(s1p, 16, 64);
    s1p += __shfl_xor(s1p, 32, 64);
    s2p += __shfl_xor(s2p, 16, 64);
    s2p += __shfl_xor(s2p, 32, 64);
    if (lane < 16) {
        s1[i_base + lane] = s1p;
        s2[i_base + lane] = s2p;
    }

#pragma unroll
    for (int t = 0; t < 16; ++t)
#pragma unroll
        for (int r = 0; r < 4; ++r)
            WhT[(size_t)(t * 16 + l15) * NNODES + i_base + q * 4 + r] = f2bf(acc[t][r]);
}

// ---------------- Kernel 2: fused masked-softmax attention @ Wh ----------------
// grid 256 blocks x 512 threads. Block: 32 rows x 256 cols, K-step = 128, 64 steps.
// One barrier per step (double-buffered P); adj loads issued at step top so the
// compiler's vmcnt(0)-before-barrier drain overlaps ~900 cyc of step work.
__global__ __launch_bounds__(512, 2) void attn_kernel(
    const int* __restrict__ adj, const unsigned short* __restrict__ WhT,
    const float* __restrict__ s1, const float* __restrict__ s2,
    float* __restrict__ out)
{
    __shared__ float s2_lds[NNODES];                 // 32 KB
    __shared__ unsigned short P_lds[2][32 * 128];    // 2 x 8 KB, A-frag-linear order
    __shared__ float dsum_lds[32][16];
    __shared__ float rinv_lds[32];

    int tid = threadIdx.x;
    int blk = blockIdx.x;

    // stage s2 (32 KB fp32)
    for (int i = tid; i < NNODES / 4; i += 512)
        ((v4f*)s2_lds)[i] = ((const v4f*)s2)[i];

    // P-generator role: thread = (row m, k-slice idx); covers k = kstep*128 + idx*8 .. +7
    int m = tid >> 4, idx = tid & 15;
    int row_g = blk * 32 + m;
    float s1v = s1[row_g];
    const int* arow = adj + (size_t)row_g * NNODES + idx * 8;
    // P slot: A-frag (c=idx>>2, q=idx&3, row m) stored at slot idx*32+m (reader-linear)
    unsigned short* pslot0 = &P_lds[0][(idx * 32 + m) * 8];
    unsigned short* pslot1 = &P_lds[1][(idx * 32 + m) * 8];

    // MFMA role: wave w -> colgroup g = w&3 (cols g*64+t*16+l15), rowhalf rh = w>>2
    int w = tid >> 6, lane = tid & 63, q = lane >> 4, l15 = lane & 15;
    int g = w & 3, rh = w >> 2;
    const unsigned short* bb[4];
#pragma unroll
    for (int t = 0; t < 4; ++t)
        bb[t] = WhT + (size_t)(g * 64 + t * 16 + l15) * NNODES + q * 8;

    f4v acc[4] = {};
    float dsum = 0.0f;

    // prologue: adj step0 -> gen P step0; adj step1 stays in cur
    v4i a0 = __builtin_nontemporal_load((const v4i*)(arow));
    v4i a1 = __builtin_nontemporal_load((const v4i*)(arow + 4));
    v4i cur0 = __builtin_nontemporal_load((const v4i*)(arow + 128));
    v4i cur1 = __builtin_nontemporal_load((const v4i*)(arow + 132));
    {
        int kb = idx * 8;
        v4f sA = *(const v4f*)&s2_lds[kb];
        v4f sB = *(const v4f*)&s2_lds[kb + 4];
        s8v pv;
#pragma unroll
        for (int j = 0; j < 4; ++j) {
            float x = s1v + sA[j];
            float e = fmaxf(x, 0.2f * x);
            float p = (a0[j] > 0) ? __expf(e) : 0.0f;
            unsigned short pb = f2bf(p);
            pv[j] = (short)pb; dsum += bf2f(pb);
            float x2 = s1v + sB[j];
            float e2 = fmaxf(x2, 0.2f * x2);
            float p2 = (a1[j] > 0) ? __expf(e2) : 0.0f;
            unsigned short pb2 = f2bf(p2);
            pv[4 + j] = (short)pb2; dsum += bf2f(pb2);
        }
        *(s8v*)pslot0 = pv;
    }
    __syncthreads();

    for (int s = 0; s < 64; ++s) {
        int k0 = s * 128;
        // 1) issue adj for step s+2 first (max distance to the barrier drain)
        int kn = (s < 62) ? (k0 + 256) : 0;
        v4i nx0 = __builtin_nontemporal_load((const v4i*)(arow + kn));
        v4i nx1 = __builtin_nontemporal_load((const v4i*)(arow + kn + 4));

        // 2) B-frags for step s (L2-resident WhT)
        s8v bf[4][4];
#pragma unroll
        for (int c = 0; c < 4; ++c)
#pragma unroll
            for (int t = 0; t < 4; ++t)
                bf[c][t] = *(const s8v*)(bb[t] + k0 + c * 32);

        // 3) generate P for step s+1 from cur (loaded last step, drained by barrier)
        if (s < 63) {
            int kb = k0 + 128 + idx * 8;
            v4f sA = *(const v4f*)&s2_lds[kb];
            v4f sB = *(const v4f*)&s2_lds[kb + 4];
            s8v pv;
#pragma unroll
            for (int j = 0; j < 4; ++j) {
                float x = s1v + sA[j];
                float e = fmaxf(x, 0.2f * x);
                float p = (cur0[j] > 0) ? __expf(e) : 0.0f;
                unsigned short pb = f2bf(p);
                pv[j] = (short)pb; dsum += bf2f(pb);
                float x2 = s1v + sB[j];
                float e2 = fmaxf(x2, 0.2f * x2);
                float p2 = (cur1[j] > 0) ? __expf(e2) : 0.0f;
                unsigned short pb2 = f2bf(p2);
                pv[4 + j] = (short)pb2; dsum += bf2f(pb2);
            }
            *(s8v*)(((s + 1) & 1) ? pslot1 : pslot0) = pv;
        }

        // 4) A-frags for step s: slot (c*4+q)*32 + rh*16 + l15 -> linear in l15
        const unsigned short* pbuf = P_lds[s & 1];
        s8v af[4];
#pragma unroll
        for (int c = 0; c < 4; ++c)
            af[c] = *(const s8v*)&pbuf[((c * 4 + q) * 32 + rh * 16 + l15) * 8];

        // 5) MFMA
#pragma unroll
        for (int c = 0; c < 4; ++c)
#pragma unroll
            for (int t = 0; t < 4; ++t)
                acc[t] = __builtin_amdgcn_mfma_f32_16x16x32_bf16(af[c], bf[c][t], acc[t], 0, 0, 0);

        __syncthreads();
        cur0 = nx0; cur1 = nx1;
    }

    // denominator reduce
    dsum_lds[m][idx] = dsum;
    __syncthreads();
    if (tid < 32) {
        float d = 0.f;
#pragma unroll
        for (int j = 0; j < 16; ++j) d += dsum_lds[tid][j];
        rinv_lds[tid] = 1.0f / fmaxf(d, 1e-30f);
    }
    __syncthreads();

    // epilogue: row = rh*16 + q*4 + r, col = g*64 + t*16 + l15
#pragma unroll
    for (int r = 0; r < 4; ++r) {
        int rl = rh * 16 + q * 4 + r;
        float ri = rinv_lds[rl];
        size_t orow = (size_t)(blk * 32 + rl) * FDIM;
#pragma unroll
        for (int t = 0; t < 4; ++t)
            out[orow + g * 64 + t * 16 + l15] = acc[t][r] * ri;
    }
}

extern "C" void kernel_launch(void* const* d_in, const int* in_sizes, int n_in,
                              void* d_out, int out_size, void* d_ws, size_t ws_size,
                              hipStream_t stream) {
    const float* h   = (const float*)d_in[0];
    const int*   adj = (const int*)d_in[1];
    const float* W   = (const float*)d_in[2];
    const float* a   = (const float*)d_in[3];
    float* out = (float*)d_out;

    char* ws = (char*)d_ws;
    unsigned short* WhT = (unsigned short*)ws;                        // 4 MiB
    float* s1 = (float*)(ws + (4u << 20));                            // 32 KiB
    float* s2 = (float*)(ws + (4u << 20) + 32768);                    // 32 KiB
    unsigned short* WT = (unsigned short*)(ws + (4u << 20) + 65536);  // 128 KiB
    float* v1 = (float*)(ws + (4u << 20) + 65536 + 131072);           // 1 KiB
    float* v2 = (float*)(ws + (4u << 20) + 65536 + 131072 + 1024);    // 1 KiB

    hipLaunchKernelGGL(wt_kernel, dim3(256), dim3(256), 0, stream, W, WT);
    hipLaunchKernelGGL(wv_kernel, dim3(256), dim3(256), 0, stream, W, a, v1, v2);
    hipLaunchKernelGGL(wh_kernel, dim3(128), dim3(256), 0, stream, h, WT, v1, v2, WhT, s1, s2);
    hipLaunchKernelGGL(attn_kernel, dim3(256), dim3(512), 0, stream, adj, WhT, s1, s2, out);
}